// Round 1
// baseline (618.905 us; speedup 1.0000x reference)
//
#include <hip/hip_runtime.h>
#include <hip/hip_bf16.h>

#define Bn 4
#define Ln 4096
#define Dn 1024
#define Hn 16
#define KSEL 41

// ---------------- column sums of q and k ----------------
// grid (4, 32, 8): x = d-chunk(256), y = t-chunk(128 rows), z = tensor*4 + b
__global__ void colsum_part(const float* __restrict__ q, const float* __restrict__ k,
                            float* __restrict__ part) {
    int tb = blockIdx.z; int tensor = tb >> 2, b = tb & 3;
    const float* src = (tensor ? k : q) + (size_t)b * Ln * Dn;
    int d  = blockIdx.x * 256 + threadIdx.x;
    int t0 = blockIdx.y * 128;
    float s = 0.f;
    for (int i = 0; i < 128; ++i) s += src[(size_t)(t0 + i) * Dn + d];
    part[((size_t)tb * 32 + blockIdx.y) * 1024 + d] = s;
}

// grid (4, 8)
__global__ void colsum_fin(const float* __restrict__ part, float* __restrict__ sums) {
    int tb = blockIdx.y; int d = blockIdx.x * 256 + threadIdx.x;
    float s = 0.f;
    for (int i = 0; i < 32; ++i) s += part[((size_t)tb * 32 + i) * 1024 + d];
    sums[(size_t)tb * 1024 + d] = s;
}

// ---------------- SQ/SK = colsum @ W^T + L*bias ----------------
// grid (64, 2); block 256 (4 waves). Wave handles 4 rows; all 4 b at once.
__global__ void proj_sums(const float* __restrict__ sums,
                          const float* __restrict__ Wq, const float* __restrict__ bq,
                          const float* __restrict__ Wk, const float* __restrict__ bk,
                          float* __restrict__ SQK) {
    int t = blockIdx.y;
    const float* W    = t ? Wk : Wq;
    const float* bias = t ? bk : bq;
    const float* sv   = sums + (size_t)t * 4 * 1024;
    __shared__ float s_sv[4 * 1024];
    for (int i = threadIdx.x; i < 4 * 1024; i += 256) s_sv[i] = sv[i];
    __syncthreads();
    int wave = threadIdx.x >> 6, lane = threadIdx.x & 63;
    for (int rr = 0; rr < 4; ++rr) {
        int j = blockIdx.x * 16 + rr * 4 + wave;
        float p[4] = {0.f, 0.f, 0.f, 0.f};
        for (int c = 0; c < 4; ++c) {
            float4 wv = *(const float4*)(W + (size_t)j * 1024 + c * 256 + lane * 4);
            #pragma unroll
            for (int b = 0; b < 4; ++b) {
                float4 s = *(const float4*)(s_sv + b * 1024 + c * 256 + lane * 4);
                p[b] += wv.x * s.x + wv.y * s.y + wv.z * s.z + wv.w * s.w;
            }
        }
        #pragma unroll
        for (int b = 0; b < 4; ++b)
            for (int off = 1; off < 64; off <<= 1) p[b] += __shfl_xor(p[b], off);
        if (lane == 0) {
            float bb = bias[j] * (float)Ln;
            #pragma unroll
            for (int b = 0; b < 4; ++b) SQK[((size_t)t * 4 + b) * 1024 + j] = p[b] + bb;
        }
    }
}

// ---------------- mean_value[b][c] ----------------
__global__ void meanval_k(const float* __restrict__ SQK, float* __restrict__ mv) {
    int tid = threadIdx.x; int b = tid >> 6, c = tid & 63;
    const float* SQ = SQK; const float* SK = SQK + 4 * 1024;
    float s = 0.f;
    for (int h = 0; h < Hn; ++h)
        s += SQ[(size_t)b * 1024 + h * 64 + c] * SK[(size_t)b * 1024 + h * 64 + c];
    mv[tid] = s * (1.0f / ((float)Hn * (float)Ln));
}

// ---------------- top-41 + per-b softmax ----------------
__global__ void topk_k(const float* __restrict__ mv, int* __restrict__ dly,
                       float* __restrict__ wts) {
    __shared__ float mab[64];
    __shared__ float selv[4][KSEL];
    int c = threadIdx.x;  // 64 threads
    float m0 = mv[c], m1 = mv[64 + c], m2 = mv[128 + c], m3 = mv[192 + c];
    mab[c] = (m0 + m1 + m2 + m3) * 0.25f;
    __syncthreads();
    float my = mab[c];
    int rank = 0;
    for (int j = 0; j < 64; ++j) {
        float vj = mab[j];
        rank += (vj > my) || (vj == my && j < c);
    }
    if (rank < KSEL) {
        dly[rank] = c;
        selv[0][rank] = m0; selv[1][rank] = m1; selv[2][rank] = m2; selv[3][rank] = m3;
    }
    __syncthreads();
    if (c < 4) {
        float mx = -1e30f;
        for (int i = 0; i < KSEL; ++i) mx = fmaxf(mx, selv[c][i]);
        float s = 0.f;
        for (int i = 0; i < KSEL; ++i) s += __expf(selv[c][i] - mx);
        // use expf for accuracy:
        s = 0.f;
        for (int i = 0; i < KSEL; ++i) s += expf(selv[c][i] - mx);
        float inv = 1.0f / s;
        for (int i = 0; i < KSEL; ++i) wts[c * 64 + i] = expf(selv[c][i] - mx) * inv;
    }
}

// ---------------- 1024x1024 transpose (for Wv) ----------------
__global__ void transpose1024(const float* __restrict__ in, float* __restrict__ out) {
    __shared__ float t[32][33];
    int bx = blockIdx.x * 32, by = blockIdx.y * 32;
    int x = threadIdx.x, y0 = threadIdx.y;
    for (int i = 0; i < 32; i += 8) t[y0 + i][x] = in[(size_t)(by + y0 + i) * 1024 + bx + x];
    __syncthreads();
    for (int i = 0; i < 32; i += 8) out[(size_t)(bx + y0 + i) * 1024 + by + x] = t[x][y0 + i];
}

// ---------------- bc = Wo @ bv + bo ----------------
__global__ void bcvec_k(const float* __restrict__ Wo, const float* __restrict__ bv,
                        const float* __restrict__ bo, float* __restrict__ bc) {
    __shared__ float s_bv[1024];
    for (int i = threadIdx.x; i < 1024; i += 256) s_bv[i] = bv[i];
    __syncthreads();
    int wave = threadIdx.x >> 6, lane = threadIdx.x & 63;
    for (int rr = 0; rr < 4; ++rr) {
        int n = blockIdx.x * 16 + rr * 4 + wave;
        float p = 0.f;
        for (int c = 0; c < 4; ++c) {
            float4 wv = *(const float4*)(Wo + (size_t)n * 1024 + c * 256 + lane * 4);
            float4 s  = *(const float4*)(s_bv + c * 256 + lane * 4);
            p += wv.x * s.x + wv.y * s.y + wv.z * s.z + wv.w * s.w;
        }
        for (int off = 1; off < 64; off <<= 1) p += __shfl_xor(p, off);
        if (lane == 0) bc[n] = p + bo[n];
    }
}

// ---------------- generic NT GEMM: C[m,n] = sum_k A[m,k]*Bt[n,k] ----------------
template <int BM, int BN, int BK, int TM, int TN>
__global__ __launch_bounds__(256) void gemm_nt(const float* __restrict__ A,
                                               const float* __restrict__ Bt,
                                               float* __restrict__ C,
                                               int M, int N, int K) {
    constexpr int THREADS = (BM / TM) * (BN / TN);
    static_assert(THREADS == 256, "256 threads expected");
    __shared__ __align__(16) float As[BK][BM + 4];
    __shared__ __align__(16) float Bs[BK][BN + 4];
    const int tid = threadIdx.x;
    const int nTx = BN / TN;
    const int tx = tid % nTx, ty = tid / nTx;
    const int m0 = ty * TM, n0 = tx * TN;
    const int bm = blockIdx.y * BM, bn = blockIdx.x * BN;

    float acc[TM][TN];
    #pragma unroll
    for (int i = 0; i < TM; ++i)
        #pragma unroll
        for (int j = 0; j < TN; ++j) acc[i][j] = 0.f;

    constexpr int A_LOADS = BM * BK / (THREADS * 4);
    constexpr int B_LOADS = BN * BK / (THREADS * 4);

    for (int k0 = 0; k0 < K; k0 += BK) {
        #pragma unroll
        for (int i = 0; i < A_LOADS; ++i) {
            int idx = tid + i * THREADS;
            int row = idx / (BK / 4);
            int kq  = idx % (BK / 4);
            float4 va = *(const float4*)(A + (size_t)(bm + row) * K + k0 + kq * 4);
            As[kq * 4 + 0][row] = va.x; As[kq * 4 + 1][row] = va.y;
            As[kq * 4 + 2][row] = va.z; As[kq * 4 + 3][row] = va.w;
        }
        #pragma unroll
        for (int i = 0; i < B_LOADS; ++i) {
            int idx = tid + i * THREADS;
            int row = idx / (BK / 4);
            int kq  = idx % (BK / 4);
            float4 vb = *(const float4*)(Bt + (size_t)(bn + row) * K + k0 + kq * 4);
            Bs[kq * 4 + 0][row] = vb.x; Bs[kq * 4 + 1][row] = vb.y;
            Bs[kq * 4 + 2][row] = vb.z; Bs[kq * 4 + 3][row] = vb.w;
        }
        __syncthreads();
        #pragma unroll
        for (int kk = 0; kk < BK; ++kk) {
            float a[TM], b[TN];
            #pragma unroll
            for (int i = 0; i < TM; i += 4) *(float4*)&a[i] = *(const float4*)&As[kk][m0 + i];
            #pragma unroll
            for (int j = 0; j < TN; j += 4) *(float4*)&b[j] = *(const float4*)&Bs[kk][n0 + j];
            #pragma unroll
            for (int i = 0; i < TM; ++i)
                #pragma unroll
                for (int j = 0; j < TN; ++j) acc[i][j] += a[i] * b[j];
        }
        __syncthreads();
    }
    #pragma unroll
    for (int i = 0; i < TM; ++i)
        #pragma unroll
        for (int j = 0; j < TN; j += 4) {
            float4 v4 = make_float4(acc[i][j], acc[i][j + 1], acc[i][j + 2], acc[i][j + 3]);
            *(float4*)(C + (size_t)(bm + m0 + i) * N + bn + n0 + j) = v4;
        }
}

// ---------------- final gather: out[b,t,:] = sum_k w[b,k]*O[b,(t+d_k)%L,:] + bc ----------------
// grid (4096, 4), block 256 (one float4 per thread across D)
__global__ void gather_k(const float* __restrict__ O, const int* __restrict__ dly,
                         const float* __restrict__ wts, const float* __restrict__ bc,
                         float* __restrict__ out) {
    int t = blockIdx.x, b = blockIdx.y;
    __shared__ int   s_d[KSEL];
    __shared__ float s_w[KSEL];
    if (threadIdx.x < KSEL) {
        s_d[threadIdx.x] = dly[threadIdx.x];
        s_w[threadIdx.x] = wts[b * 64 + threadIdx.x];
    }
    __syncthreads();
    int c4 = threadIdx.x;
    const float4* Ob = (const float4*)(O + (size_t)b * Ln * Dn);
    float4 acc = ((const float4*)bc)[c4];
    for (int kk = 0; kk < KSEL; ++kk) {
        int row = t + s_d[kk];
        if (row >= Ln) row -= Ln;
        float4 v = Ob[(size_t)row * 256 + c4];
        float w = s_w[kk];
        acc.x += w * v.x; acc.y += w * v.y; acc.z += w * v.z; acc.w += w * v.w;
    }
    ((float4*)out)[((size_t)b * Ln + t) * 256 + c4] = acc;
}

extern "C" void kernel_launch(void* const* d_in, const int* in_sizes, int n_in,
                              void* d_out, int out_size, void* d_ws, size_t ws_size,
                              hipStream_t stream) {
    const float* q  = (const float*)d_in[0];
    const float* k  = (const float*)d_in[1];
    const float* v  = (const float*)d_in[2];
    const float* Wq = (const float*)d_in[3];
    const float* bq = (const float*)d_in[4];
    const float* Wk = (const float*)d_in[5];
    const float* bk = (const float*)d_in[6];
    const float* Wv = (const float*)d_in[7];
    const float* bv = (const float*)d_in[8];
    const float* Wo = (const float*)d_in[9];
    const float* bo = (const float*)d_in[10];
    float* out = (float*)d_out;

    float* ws   = (float*)d_ws;
    float* O    = ws;                    // 16777216
    float* Wc   = O + 16777216;          // 1048576
    float* WvT  = Wc + 1048576;          // 1048576
    float* part = WvT + 1048576;         // 262144
    float* sums = part + 262144;         // 8192  ([2][4][1024])
    float* SQK  = sums + 8192;           // 8192
    float* mv   = SQK + 8192;            // 256
    float* wts  = mv + 256;              // 256
    float* bc   = wts + 256;             // 1024
    int*   dly  = (int*)(bc + 1024);     // 64

    // correlation-stats chain (cheap)
    hipLaunchKernelGGL(colsum_part, dim3(4, 32, 8), dim3(256), 0, stream, q, k, part);
    hipLaunchKernelGGL(colsum_fin, dim3(4, 8), dim3(256), 0, stream, part, sums);
    hipLaunchKernelGGL(proj_sums, dim3(64, 2), dim3(256), 0, stream, sums, Wq, bq, Wk, bk, SQK);
    hipLaunchKernelGGL(meanval_k, dim3(1), dim3(256), 0, stream, SQK, mv);
    hipLaunchKernelGGL(topk_k, dim3(1), dim3(64), 0, stream, mv, dly, wts);

    // fused weight Wc = Wo @ Wv (as NT: Wc[n,k] = sum_j Wo[n,j] * WvT[k,j])
    hipLaunchKernelGGL(transpose1024, dim3(32, 32), dim3(32, 8), 0, stream, Wv, WvT);
    hipLaunchKernelGGL((gemm_nt<64, 64, 32, 4, 4>), dim3(16, 16), dim3(256), 0, stream,
                       Wo, WvT, Wc, 1024, 1024, 1024);
    hipLaunchKernelGGL(bcvec_k, dim3(64), dim3(256), 0, stream, Wo, bv, bo, bc);

    // big GEMM: O = v @ Wc^T  (16384 x 1024 x 1024)
    hipLaunchKernelGGL((gemm_nt<128, 128, 32, 8, 8>), dim3(8, 128), dim3(256), 0, stream,
                       v, Wc, O, Bn * Ln, 1024, 1024);

    // weighted delay gather + bias
    hipLaunchKernelGGL(gather_k, dim3(4096, 4), dim3(256), 0, stream, O, dly, wts, bc, out);
}

// Round 2
// 291.046 us; speedup vs baseline: 2.1265x; 2.1265x over previous
//
#include <hip/hip_runtime.h>
#include <hip/hip_bf16.h>

#define Bn 4
#define Ln 4096
#define Dn 1024
#define Hn 16
#define KSEL 41

typedef __attribute__((ext_vector_type(8))) short bf16x8;
typedef __attribute__((ext_vector_type(4))) float f32x4;

// ---------- bf16 helpers (RNE, bit-level, no API dependence) ----------
__device__ __forceinline__ unsigned short f2bf(float f) {
    unsigned u = __float_as_uint(f);
    unsigned r = (u + 0x7fffu + ((u >> 16) & 1u)) >> 16;
    return (unsigned short)r;
}
__device__ __forceinline__ float bf2f(unsigned short h) {
    return __uint_as_float(((unsigned)h) << 16);
}

// ---------- async global->LDS, 16B per lane ----------
__device__ __forceinline__ void gl2lds16(const unsigned short* g, unsigned short* l) {
    __builtin_amdgcn_global_load_lds(
        (const __attribute__((address_space(1))) unsigned int*)(uintptr_t)g,
        (__attribute__((address_space(3))) unsigned int*)(uintptr_t)l,
        16, 0, 0);
}

// ---------------- column sums of q and k (vectorized) ----------------
// grid (32, 8): x = t-chunk(128 rows), y = tensor*4 + b ; 256 thr = 1024 d via float4
__global__ void colsum_part(const float* __restrict__ q, const float* __restrict__ k,
                            float* __restrict__ part) {
    int tb = blockIdx.y; int tensor = tb >> 2, b = tb & 3;
    const float4* src = (const float4*)((tensor ? k : q) + (size_t)b * Ln * Dn);
    int d4 = threadIdx.x;
    int t0 = blockIdx.x * 128;
    float sx = 0.f, sy = 0.f, sz = 0.f, sw = 0.f;
    for (int i = 0; i < 128; ++i) {
        float4 v = src[(size_t)(t0 + i) * 256 + d4];
        sx += v.x; sy += v.y; sz += v.z; sw += v.w;
    }
    float4 o; o.x = sx; o.y = sy; o.z = sz; o.w = sw;
    ((float4*)part)[((size_t)tb * 32 + blockIdx.x) * 256 + d4] = o;
}

// grid (4, 8)
__global__ void colsum_fin(const float* __restrict__ part, float* __restrict__ sums) {
    int tb = blockIdx.y; int d = blockIdx.x * 256 + threadIdx.x;
    float s = 0.f;
    for (int i = 0; i < 32; ++i) s += part[((size_t)tb * 32 + i) * 1024 + d];
    sums[(size_t)tb * 1024 + d] = s;
}

// ---------------- SQ/SK = colsum @ W^T + L*bias ----------------
__global__ void proj_sums(const float* __restrict__ sums,
                          const float* __restrict__ Wq, const float* __restrict__ bq,
                          const float* __restrict__ Wk, const float* __restrict__ bk,
                          float* __restrict__ SQK) {
    int t = blockIdx.y;
    const float* W    = t ? Wk : Wq;
    const float* bias = t ? bk : bq;
    const float* sv   = sums + (size_t)t * 4 * 1024;
    __shared__ float s_sv[4 * 1024];
    for (int i = threadIdx.x; i < 4 * 1024; i += 256) s_sv[i] = sv[i];
    __syncthreads();
    int wave = threadIdx.x >> 6, lane = threadIdx.x & 63;
    for (int rr = 0; rr < 4; ++rr) {
        int j = blockIdx.x * 16 + rr * 4 + wave;
        float p[4] = {0.f, 0.f, 0.f, 0.f};
        for (int c = 0; c < 4; ++c) {
            float4 wv = *(const float4*)(W + (size_t)j * 1024 + c * 256 + lane * 4);
            #pragma unroll
            for (int b = 0; b < 4; ++b) {
                float4 s = *(const float4*)(s_sv + b * 1024 + c * 256 + lane * 4);
                p[b] += wv.x * s.x + wv.y * s.y + wv.z * s.z + wv.w * s.w;
            }
        }
        #pragma unroll
        for (int b = 0; b < 4; ++b)
            for (int off = 1; off < 64; off <<= 1) p[b] += __shfl_xor(p[b], off);
        if (lane == 0) {
            float bb = bias[j] * (float)Ln;
            #pragma unroll
            for (int b = 0; b < 4; ++b) SQK[((size_t)t * 4 + b) * 1024 + j] = p[b] + bb;
        }
    }
}

// ---------------- mean_value[b][c] ----------------
__global__ void meanval_k(const float* __restrict__ SQK, float* __restrict__ mv) {
    int tid = threadIdx.x; int b = tid >> 6, c = tid & 63;
    const float* SQ = SQK; const float* SK = SQK + 4 * 1024;
    float s = 0.f;
    for (int h = 0; h < Hn; ++h)
        s += SQ[(size_t)b * 1024 + h * 64 + c] * SK[(size_t)b * 1024 + h * 64 + c];
    mv[tid] = s * (1.0f / ((float)Hn * (float)Ln));
}

// ---------------- top-41 + per-b softmax ----------------
__global__ void topk_k(const float* __restrict__ mv, int* __restrict__ dly,
                       float* __restrict__ wts) {
    __shared__ float mab[64];
    __shared__ float selv[4][KSEL];
    int c = threadIdx.x;  // 64 threads
    float m0 = mv[c], m1 = mv[64 + c], m2 = mv[128 + c], m3 = mv[192 + c];
    mab[c] = (m0 + m1 + m2 + m3) * 0.25f;
    __syncthreads();
    float my = mab[c];
    int rank = 0;
    for (int j = 0; j < 64; ++j) {
        float vj = mab[j];
        rank += (vj > my) || (vj == my && j < c);
    }
    if (rank < KSEL) {
        dly[rank] = c;
        selv[0][rank] = m0; selv[1][rank] = m1; selv[2][rank] = m2; selv[3][rank] = m3;
    }
    __syncthreads();
    if (c < 4) {
        float mx = -1e30f;
        for (int i = 0; i < KSEL; ++i) mx = fmaxf(mx, selv[c][i]);
        float s = 0.f;
        for (int i = 0; i < KSEL; ++i) s += expf(selv[c][i] - mx);
        float inv = 1.0f / s;
        for (int i = 0; i < KSEL; ++i) wts[c * 64 + i] = expf(selv[c][i] - mx) * inv;
    }
}

// ---------------- fp32 -> (hi,lo) bf16 split ----------------
__global__ void split_fp32(const float* __restrict__ x, unsigned short* __restrict__ hi,
                           unsigned short* __restrict__ lo, int n4) {
    int i = blockIdx.x * 256 + threadIdx.x;
    if (i >= n4) return;
    float4 v = ((const float4*)x)[i];
    ushort4 h, l;
    h.x = f2bf(v.x); l.x = f2bf(v.x - bf2f(h.x));
    h.y = f2bf(v.y); l.y = f2bf(v.y - bf2f(h.y));
    h.z = f2bf(v.z); l.z = f2bf(v.z - bf2f(h.z));
    h.w = f2bf(v.w); l.w = f2bf(v.w - bf2f(h.w));
    ((ushort4*)hi)[i] = h; ((ushort4*)lo)[i] = l;
}

// ---------------- 1024x1024 transpose (fp32 out, fallback) ----------------
__global__ void transpose1024(const float* __restrict__ in, float* __restrict__ out) {
    __shared__ float t[32][33];
    int bx = blockIdx.x * 32, by = blockIdx.y * 32;
    int x = threadIdx.x, y0 = threadIdx.y;
    for (int i = 0; i < 32; i += 8) t[y0 + i][x] = in[(size_t)(by + y0 + i) * 1024 + bx + x];
    __syncthreads();
    for (int i = 0; i < 32; i += 8) out[(size_t)(bx + y0 + i) * 1024 + by + x] = t[x][y0 + i];
}

// ---------------- 1024x1024 transpose + split ----------------
__global__ void transpose_split(const float* __restrict__ in, unsigned short* __restrict__ oh,
                                unsigned short* __restrict__ ol) {
    __shared__ float t[32][33];
    int bx = blockIdx.x * 32, by = blockIdx.y * 32;
    int x = threadIdx.x, y0 = threadIdx.y;
    for (int i = 0; i < 32; i += 8) t[y0 + i][x] = in[(size_t)(by + y0 + i) * 1024 + bx + x];
    __syncthreads();
    for (int i = 0; i < 32; i += 8) {
        float v = t[x][y0 + i];
        unsigned short h = f2bf(v);
        unsigned short l = f2bf(v - bf2f(h));
        size_t idx = (size_t)(bx + y0 + i) * 1024 + by + x;
        oh[idx] = h; ol[idx] = l;
    }
}

// ---------------- bc = Wo @ bv + bo ----------------
__global__ void bcvec_k(const float* __restrict__ Wo, const float* __restrict__ bv,
                        const float* __restrict__ bo, float* __restrict__ bc) {
    __shared__ float s_bv[1024];
    for (int i = threadIdx.x; i < 1024; i += 256) s_bv[i] = bv[i];
    __syncthreads();
    int wave = threadIdx.x >> 6, lane = threadIdx.x & 63;
    for (int rr = 0; rr < 4; ++rr) {
        int n = blockIdx.x * 16 + rr * 4 + wave;
        float p = 0.f;
        for (int c = 0; c < 4; ++c) {
            float4 wv = *(const float4*)(Wo + (size_t)n * 1024 + c * 256 + lane * 4);
            float4 s  = *(const float4*)(s_bv + c * 256 + lane * 4);
            p += wv.x * s.x + wv.y * s.y + wv.z * s.z + wv.w * s.w;
        }
        for (int off = 1; off < 64; off <<= 1) p += __shfl_xor(p, off);
        if (lane == 0) bc[n] = p + bo[n];
    }
}

// ---------------- bf16 split-GEMM via MFMA ----------------
// C[m,n] = sum_k (Ah+Al)[m,k]*(Bh+Bl)[n,k], dropping Al*Bl.
// Tile BM x BM, 4 waves (2x2), BK=32. m97 structure: global_load_lds + 2 barriers.
template <int BM, bool SPLIT_OUT>
__global__ __launch_bounds__(256, 2) void gemm_sp(
    const unsigned short* __restrict__ Ah, const unsigned short* __restrict__ Al,
    const unsigned short* __restrict__ Bh, const unsigned short* __restrict__ Bl,
    float* __restrict__ C, unsigned short* __restrict__ Ch, unsigned short* __restrict__ Cl,
    int N, int K, int nbx) {
    constexpr int FM = BM / 32;          // frags per wave dim (wave tile = BM/2)
    __shared__ unsigned short sAh[BM * 32];
    __shared__ unsigned short sAl[BM * 32];
    __shared__ unsigned short sBh[BM * 32];
    __shared__ unsigned short sBl[BM * 32];

    int nwg = gridDim.x;
    int bid = blockIdx.x;
    int swz = (bid % 8) * (nwg / 8) + bid / 8;   // nwg % 8 == 0 for all our grids
    int by = swz / nbx, bx = swz % nbx;

    const int wave = threadIdx.x >> 6, lane = threadIdx.x & 63;
    const int lrow = lane & 15, lk = (lane >> 4) * 8;
    const int wr = wave >> 1, wc = wave & 1;

    f32x4 acc[FM][FM];
    #pragma unroll
    for (int i = 0; i < FM; ++i)
        #pragma unroll
        for (int j = 0; j < FM; ++j) acc[i][j] = (f32x4){0.f, 0.f, 0.f, 0.f};

    const int srow = lane >> 2;          // staging row within 16-row chunk
    const int skq  = (lane & 3) * 8;     // staging k offset (bf16 elems)

    for (int k0 = 0; k0 < K; k0 += 32) {
        // ---- stage 4 tiles (BM x 32 bf16 each) ----
        #pragma unroll
        for (int j = 0; j < BM / 64; ++j) {
            int chunk = j * 4 + wave;                 // 16-row chunk
            int row = chunk * 16 + srow;
            size_t goffA = (size_t)((by * BM) + row) * K + k0 + skq;
            size_t goffB = (size_t)((bx * BM) + row) * K + k0 + skq;
            gl2lds16(Ah + goffA, sAh + chunk * 512);
            gl2lds16(Al + goffA, sAl + chunk * 512);
            gl2lds16(Bh + goffB, sBh + chunk * 512);
            gl2lds16(Bl + goffB, sBl + chunk * 512);
        }
        __syncthreads();
        // ---- fragments + MFMA ----
        bf16x8 bh[FM], bl[FM];
        #pragma unroll
        for (int j = 0; j < FM; ++j) {
            int r = wc * (BM / 2) + j * 16 + lrow;
            bh[j] = *(const bf16x8*)&sBh[r * 32 + lk];
            bl[j] = *(const bf16x8*)&sBl[r * 32 + lk];
        }
        #pragma unroll
        for (int i = 0; i < FM; ++i) {
            int r = wr * (BM / 2) + i * 16 + lrow;
            bf16x8 ah = *(const bf16x8*)&sAh[r * 32 + lk];
            bf16x8 al = *(const bf16x8*)&sAl[r * 32 + lk];
            #pragma unroll
            for (int j = 0; j < FM; ++j) {
                acc[i][j] = __builtin_amdgcn_mfma_f32_16x16x32_bf16(ah, bh[j], acc[i][j], 0, 0, 0);
                acc[i][j] = __builtin_amdgcn_mfma_f32_16x16x32_bf16(al, bh[j], acc[i][j], 0, 0, 0);
                acc[i][j] = __builtin_amdgcn_mfma_f32_16x16x32_bf16(ah, bl[j], acc[i][j], 0, 0, 0);
            }
        }
        __syncthreads();
    }
    // ---- epilogue: C row=(lane>>4)*4+reg, col=lane&15 ----
    #pragma unroll
    for (int i = 0; i < FM; ++i) {
        int r0 = by * BM + wr * (BM / 2) + i * 16 + (lane >> 4) * 4;
        #pragma unroll
        for (int j = 0; j < FM; ++j) {
            int c = bx * BM + wc * (BM / 2) + j * 16 + (lane & 15);
            #pragma unroll
            for (int r = 0; r < 4; ++r) {
                float v = acc[i][j][r];
                size_t idx = (size_t)(r0 + r) * N + c;
                if (SPLIT_OUT) {
                    unsigned short h = f2bf(v);
                    Ch[idx] = h; Cl[idx] = f2bf(v - bf2f(h));
                } else {
                    C[idx] = v;
                }
            }
        }
    }
}

// ---------------- fp32 NT GEMM (fallback path) ----------------
template <int BM, int BN, int BK, int TM, int TN>
__global__ __launch_bounds__(256) void gemm_nt(const float* __restrict__ A,
                                               const float* __restrict__ Bt,
                                               float* __restrict__ C,
                                               int M, int N, int K) {
    constexpr int THREADS = (BM / TM) * (BN / TN);
    static_assert(THREADS == 256, "256 threads expected");
    __shared__ __align__(16) float As[BK][BM + 4];
    __shared__ __align__(16) float Bs[BK][BN + 4];
    const int tid = threadIdx.x;
    const int nTx = BN / TN;
    const int tx = tid % nTx, ty = tid / nTx;
    const int m0 = ty * TM, n0 = tx * TN;
    const int bm = blockIdx.y * BM, bn = blockIdx.x * BN;

    float acc[TM][TN];
    #pragma unroll
    for (int i = 0; i < TM; ++i)
        #pragma unroll
        for (int j = 0; j < TN; ++j) acc[i][j] = 0.f;

    constexpr int A_LOADS = BM * BK / (THREADS * 4);
    constexpr int B_LOADS = BN * BK / (THREADS * 4);

    for (int k0 = 0; k0 < K; k0 += BK) {
        #pragma unroll
        for (int i = 0; i < A_LOADS; ++i) {
            int idx = tid + i * THREADS;
            int row = idx / (BK / 4);
            int kq  = idx % (BK / 4);
            float4 va = *(const float4*)(A + (size_t)(bm + row) * K + k0 + kq * 4);
            As[kq * 4 + 0][row] = va.x; As[kq * 4 + 1][row] = va.y;
            As[kq * 4 + 2][row] = va.z; As[kq * 4 + 3][row] = va.w;
        }
        #pragma unroll
        for (int i = 0; i < B_LOADS; ++i) {
            int idx = tid + i * THREADS;
            int row = idx / (BK / 4);
            int kq  = idx % (BK / 4);
            float4 vb = *(const float4*)(Bt + (size_t)(bn + row) * K + k0 + kq * 4);
            Bs[kq * 4 + 0][row] = vb.x; Bs[kq * 4 + 1][row] = vb.y;
            Bs[kq * 4 + 2][row] = vb.z; Bs[kq * 4 + 3][row] = vb.w;
        }
        __syncthreads();
        #pragma unroll
        for (int kk = 0; kk < BK; ++kk) {
            float a[TM], b[TN];
            #pragma unroll
            for (int i = 0; i < TM; i += 4) *(float4*)&a[i] = *(const float4*)&As[kk][m0 + i];
            #pragma unroll
            for (int j = 0; j < TN; j += 4) *(float4*)&b[j] = *(const float4*)&Bs[kk][n0 + j];
            #pragma unroll
            for (int i = 0; i < TM; ++i)
                #pragma unroll
                for (int j = 0; j < TN; ++j) acc[i][j] += a[i] * b[j];
        }
        __syncthreads();
    }
    #pragma unroll
    for (int i = 0; i < TM; ++i)
        #pragma unroll
        for (int j = 0; j < TN; j += 4) {
            float4 v4 = make_float4(acc[i][j], acc[i][j + 1], acc[i][j + 2], acc[i][j + 3]);
            *(float4*)(C + (size_t)(bm + m0 + i) * N + bn + n0 + j) = v4;
        }
}

// ---------------- gather: sliding-window LDS (all delays < 64) ----------------
// out[b,t,c] = sum_k w[b,k]*O[b,(t+d_k)%L,c] + bc[c]
// grid (32, 16, 4): 128 t x 64 ch per block. Stage 192 rows x 64 ch.
#define GT 128
#define GC 64
#define GR (GT + 64)
__global__ __launch_bounds__(256) void gather2(const float* __restrict__ O,
                                               const int* __restrict__ dly,
                                               const float* __restrict__ wts,
                                               const float* __restrict__ bc,
                                               float* __restrict__ out) {
    __shared__ float S[GR][GC + 4];
    __shared__ int   s_d[KSEL];
    __shared__ float s_w[KSEL];
    int b = blockIdx.z, c0 = blockIdx.y * GC, t0 = blockIdx.x * GT;
    if (threadIdx.x < KSEL) {
        s_d[threadIdx.x] = dly[threadIdx.x];
        s_w[threadIdx.x] = wts[b * 64 + threadIdx.x];
    }
    const float* Ob = O + (size_t)b * Ln * Dn;
    for (int idx = threadIdx.x; idx < GR * 16; idx += 256) {
        int r = idx >> 4, c4 = idx & 15;
        int gr = (t0 + r) & (Ln - 1);
        *(float4*)&S[r][c4 * 4] = *(const float4*)&Ob[(size_t)gr * Dn + c0 + c4 * 4];
    }
    __syncthreads();
    int c4 = threadIdx.x & 15, tg = threadIdx.x >> 4;   // tg: 16 groups x 8 t-rows
    float4 bias = *(const float4*)&bc[c0 + c4 * 4];
    float4 acc[8];
    #pragma unroll
    for (int r = 0; r < 8; ++r) acc[r] = bias;
    for (int kk = 0; kk < KSEL; ++kk) {
        int d = s_d[kk]; float w = s_w[kk];
        #pragma unroll
        for (int r = 0; r < 8; ++r) {
            const float* p = &S[tg * 8 + r + d][c4 * 4];
            float4 v = *(const float4*)p;
            acc[r].x += w * v.x; acc[r].y += w * v.y;
            acc[r].z += w * v.z; acc[r].w += w * v.w;
        }
    }
    #pragma unroll
    for (int r = 0; r < 8; ++r)
        *(float4*)&out[((size_t)b * Ln + t0 + tg * 8 + r) * Dn + c0 + c4 * 4] = acc[r];
}

extern "C" void kernel_launch(void* const* d_in, const int* in_sizes, int n_in,
                              void* d_out, int out_size, void* d_ws, size_t ws_size,
                              hipStream_t stream) {
    const float* q  = (const float*)d_in[0];
    const float* k  = (const float*)d_in[1];
    const float* v  = (const float*)d_in[2];
    const float* Wq = (const float*)d_in[3];
    const float* bq = (const float*)d_in[4];
    const float* Wk = (const float*)d_in[5];
    const float* bk = (const float*)d_in[6];
    const float* Wv = (const float*)d_in[7];
    const float* bv = (const float*)d_in[8];
    const float* Wo = (const float*)d_in[9];
    const float* bo = (const float*)d_in[10];
    float* out = (float*)d_out;
    float* ws  = (float*)d_ws;

    // ---- fast-path ws layout (floats) ----
    const size_t NEED_F = 16777216ull       // O
                        + 8388608ull * 2    // Vhi, Vlo (ushort halves)
                        + 524288ull * 6     // Wohi/lo, WvThi/lo, Wchi/lo
                        + 262144 + 8192 + 8192 + 256 + 256 + 1024 + 64;
    bool fast = ws_size >= NEED_F * 4ull;

    if (fast) {
        float* O = ws;
        unsigned short* Vhi   = (unsigned short*)(O + 16777216);
        unsigned short* Vlo   = Vhi + 16777216;
        unsigned short* Wohi  = (unsigned short*)(O + 16777216 + 16777216);
        unsigned short* Wolo  = Wohi + 1048576;
        unsigned short* WvThi = Wolo + 1048576;
        unsigned short* WvTlo = WvThi + 1048576;
        unsigned short* Wchi  = WvTlo + 1048576;
        unsigned short* Wclo  = Wchi + 1048576;
        float* part = (float*)(Wclo + 1048576);
        float* sums = part + 262144;
        float* SQK  = sums + 8192;
        float* mv   = SQK + 8192;
        float* wts  = mv + 256;
        float* bc   = wts + 256;
        int*   dly  = (int*)(bc + 1024);

        // splits
        hipLaunchKernelGGL(split_fp32, dim3(16384), dim3(256), 0, stream, v, Vhi, Vlo, 4194304);
        hipLaunchKernelGGL(split_fp32, dim3(1024), dim3(256), 0, stream, Wo, Wohi, Wolo, 262144);
        hipLaunchKernelGGL(transpose_split, dim3(32, 32), dim3(32, 8), 0, stream, Wv, WvThi, WvTlo);

        // correlation-stats chain
        hipLaunchKernelGGL(colsum_part, dim3(32, 8), dim3(256), 0, stream, q, k, part);
        hipLaunchKernelGGL(colsum_fin, dim3(4, 8), dim3(256), 0, stream, part, sums);
        hipLaunchKernelGGL(proj_sums, dim3(64, 2), dim3(256), 0, stream, sums, Wq, bq, Wk, bk, SQK);
        hipLaunchKernelGGL(meanval_k, dim3(1), dim3(256), 0, stream, SQK, mv);
        hipLaunchKernelGGL(topk_k, dim3(1), dim3(64), 0, stream, mv, dly, wts);

        // Wc = Wo @ Wv  (A=Wo, Bt=WvT), split-bf16 output
        hipLaunchKernelGGL((gemm_sp<64, true>), dim3(256), dim3(256), 0, stream,
                           Wohi, Wolo, WvThi, WvTlo, (float*)nullptr, Wchi, Wclo,
                           1024, 1024, 16);
        hipLaunchKernelGGL(bcvec_k, dim3(64), dim3(256), 0, stream, Wo, bv, bo, bc);

        // O = v @ Wc^T  (16384 x 1024 x 1024)
        hipLaunchKernelGGL((gemm_sp<128, false>), dim3(1024), dim3(256), 0, stream,
                           Vhi, Vlo, Wchi, Wclo, O, (unsigned short*)nullptr,
                           (unsigned short*)nullptr, 1024, 1024, 8);

        hipLaunchKernelGGL(gather2, dim3(32, 16, 4), dim3(256), 0, stream, O, dly, wts, bc, out);
    } else {
        // fallback: round-1 fp32 path + new gather
        float* O    = ws;
        float* Wc   = O + 16777216;
        float* WvT  = Wc + 1048576;
        float* part = WvT + 1048576;
        float* sums = part + 262144;
        float* SQK  = sums + 8192;
        float* mv   = SQK + 8192;
        float* wts  = mv + 256;
        float* bc   = wts + 256;
        int*   dly  = (int*)(bc + 1024);

        hipLaunchKernelGGL(colsum_part, dim3(32, 8), dim3(256), 0, stream, q, k, part);
        hipLaunchKernelGGL(colsum_fin, dim3(4, 8), dim3(256), 0, stream, part, sums);
        hipLaunchKernelGGL(proj_sums, dim3(64, 2), dim3(256), 0, stream, sums, Wq, bq, Wk, bk, SQK);
        hipLaunchKernelGGL(meanval_k, dim3(1), dim3(256), 0, stream, SQK, mv);
        hipLaunchKernelGGL(topk_k, dim3(1), dim3(64), 0, stream, mv, dly, wts);

        hipLaunchKernelGGL(transpose1024, dim3(32, 32), dim3(32, 8), 0, stream, Wv, WvT);
        hipLaunchKernelGGL((gemm_nt<64, 64, 32, 4, 4>), dim3(16, 16), dim3(256), 0, stream,
                           Wo, WvT, Wc, 1024, 1024, 1024);
        hipLaunchKernelGGL(bcvec_k, dim3(64), dim3(256), 0, stream, Wo, bv, bo, bc);
        hipLaunchKernelGGL((gemm_nt<128, 128, 32, 8, 8>), dim3(8, 128), dim3(256), 0, stream,
                           v, Wc, O, Bn * Ln, 1024, 1024);
        hipLaunchKernelGGL(gather2, dim3(32, 16, 4), dim3(256), 0, stream, O, dly, wts, bc, out);
    }
}